// Round 1
// baseline (691.872 us; speedup 1.0000x reference)
//
#include <hip/hip_runtime.h>
#include <hip/hip_bf16.h>
#include <math.h>

#define NB 4
#define SEQ 4096
#define CDIM 768
#define HD 48

static const float SCALE = 0.14433756729740643f; // 1/sqrt(48)

// ---------------------------------------------------------------------------
// Kernel 1: projections Q,K,V = x @ W + b
// grid 256 blocks (64 rows each), 256 threads, thread tile 4 rows x 9 cols
// (144 cols = 48 q | 48 k | 48 v)
// ---------------------------------------------------------------------------
__global__ __launch_bounds__(256) void proj_kernel(
    const float* __restrict__ x,
    const float* __restrict__ Wq, const float* __restrict__ bq,
    const float* __restrict__ Wk, const float* __restrict__ bk,
    const float* __restrict__ Wv, const float* __restrict__ bv,
    float* __restrict__ Qo, float* __restrict__ Ko, float* __restrict__ Vo)
{
    __shared__ float xst[16][68];   // [c][row], transposed x tile, padded
    __shared__ float wsm[16][146];  // [c][j] j<144

    const int t  = threadIdx.x;
    const int tr = t >> 4;    // 0..15 -> rows tr*4..tr*4+3
    const int tc = t & 15;    // 0..15 -> cols tc*9..tc*9+8
    const int r0 = blockIdx.x * 64;

    float acc[4][9];
    #pragma unroll
    for (int i = 0; i < 4; ++i)
        #pragma unroll
        for (int u = 0; u < 9; ++u) acc[i][u] = 0.0f;

    for (int kc = 0; kc < 48; ++kc) {
        // stage x (64 rows x 16 c) transposed
        {
            const int row = t >> 2;
            const int cq  = (t & 3) * 4;
            const float4 xv = *reinterpret_cast<const float4*>(
                &x[(size_t)(r0 + row) * CDIM + kc * 16 + cq]);
            xst[cq + 0][row] = xv.x;
            xst[cq + 1][row] = xv.y;
            xst[cq + 2][row] = xv.z;
            xst[cq + 3][row] = xv.w;
        }
        // stage W (16 c x 144 j)
        #pragma unroll
        for (int u = 0; u < 9; ++u) {
            const int idx = u * 256 + t;    // 0..2303
            const int c = idx / 144;
            const int j = idx % 144;
            const int gr = kc * 16 + c;
            float w;
            if (j < 48)       w = Wq[gr * 48 + j];
            else if (j < 96)  w = Wk[gr * 48 + (j - 48)];
            else              w = Wv[gr * 48 + (j - 96)];
            wsm[c][j] = w;
        }
        __syncthreads();
        #pragma unroll
        for (int c = 0; c < 16; ++c) {
            const float4 xv = *reinterpret_cast<const float4*>(&xst[c][tr * 4]);
            float wv[9];
            #pragma unroll
            for (int u = 0; u < 9; ++u) wv[u] = wsm[c][tc * 9 + u];
            #pragma unroll
            for (int u = 0; u < 9; ++u) {
                acc[0][u] = fmaf(xv.x, wv[u], acc[0][u]);
                acc[1][u] = fmaf(xv.y, wv[u], acc[1][u]);
                acc[2][u] = fmaf(xv.z, wv[u], acc[2][u]);
                acc[3][u] = fmaf(xv.w, wv[u], acc[3][u]);
            }
        }
        __syncthreads();
    }
    // store with bias
    #pragma unroll
    for (int u = 0; u < 9; ++u) {
        const int j   = tc * 9 + u;
        const int mat = j / 48;
        const int jj  = j % 48;
        const float bias = (mat == 0 ? bq : (mat == 1 ? bk : bv))[jj];
        float* outp = (mat == 0 ? Qo : (mat == 1 ? Ko : Vo));
        #pragma unroll
        for (int i = 0; i < 4; ++i) {
            outp[(size_t)(r0 + tr * 4 + i) * HD + jj] = acc[i][u] + bias;
        }
    }
}

// stage a 64x48 row-major block transposed into T[48][68]
__device__ __forceinline__ void stage_T(const float* __restrict__ src,
                                        float (*T)[68], int t)
{
    #pragma unroll
    for (int i = 0; i < 3; ++i) {
        const int idx = i * 256 + t;   // 0..767
        const int row = idx / 12;
        const int seg = idx % 12;
        const float4 v = *reinterpret_cast<const float4*>(src + (size_t)row * HD + seg * 4);
        T[seg * 4 + 0][row] = v.x;
        T[seg * 4 + 1][row] = v.y;
        T[seg * 4 + 2][row] = v.z;
        T[seg * 4 + 3][row] = v.w;
    }
}

// ---------------------------------------------------------------------------
// Kernel 2: per-(b,k) column stats: m_k = max_q S, l_k = sum_q exp(S-m_k)
// grid (64 ktiles, 4 b), 256 threads; thread = (tq 0..15, tk 0..15), 4x4 tile
// ---------------------------------------------------------------------------
__global__ __launch_bounds__(256) void stats_kernel(
    const float* __restrict__ Q, const float* __restrict__ K,
    float* __restrict__ mg, float* __restrict__ lg)
{
    __shared__ float Kt[48][68];
    __shared__ float Qt[48][68];
    __shared__ float redm[16][64];
    __shared__ float redl[16][64];

    const int t  = threadIdx.x;
    const int b  = blockIdx.y;
    const int k0 = blockIdx.x * 64;
    const int tq = t >> 4, tk = t & 15;

    stage_T(K + ((size_t)b * SEQ + k0) * HD, Kt, t);

    float m_loc[4], l_loc[4];
    #pragma unroll
    for (int j = 0; j < 4; ++j) { m_loc[j] = -__builtin_inff(); l_loc[j] = 0.0f; }

    for (int qt = 0; qt < 64; ++qt) {
        __syncthreads();   // protect Qt (and initial Kt staging on qt=0 path)
        stage_T(Q + ((size_t)b * SEQ + qt * 64) * HD, Qt, t);
        __syncthreads();

        float acc[4][4];
        #pragma unroll
        for (int i = 0; i < 4; ++i)
            #pragma unroll
            for (int j = 0; j < 4; ++j) acc[i][j] = 0.0f;

        #pragma unroll
        for (int c = 0; c < 48; ++c) {
            const float4 qv = *reinterpret_cast<const float4*>(&Qt[c][tq * 4]);
            const float4 kv = *reinterpret_cast<const float4*>(&Kt[c][tk * 4]);
            const float qa[4] = {qv.x, qv.y, qv.z, qv.w};
            const float ka[4] = {kv.x, kv.y, kv.z, kv.w};
            #pragma unroll
            for (int i = 0; i < 4; ++i)
                #pragma unroll
                for (int j = 0; j < 4; ++j)
                    acc[i][j] = fmaf(qa[i], ka[j], acc[i][j]);
        }
        #pragma unroll
        for (int j = 0; j < 4; ++j) {
            const float s0 = acc[0][j] * SCALE;
            const float s1 = acc[1][j] * SCALE;
            const float s2 = acc[2][j] * SCALE;
            const float s3 = acc[3][j] * SCALE;
            const float tmax = fmaxf(fmaxf(s0, s1), fmaxf(s2, s3));
            const float nm = fmaxf(m_loc[j], tmax);
            const float corr = __expf(m_loc[j] - nm);
            l_loc[j] = l_loc[j] * corr +
                       __expf(s0 - nm) + __expf(s1 - nm) +
                       __expf(s2 - nm) + __expf(s3 - nm);
            m_loc[j] = nm;
        }
    }

    #pragma unroll
    for (int j = 0; j < 4; ++j) {
        redm[tq][tk * 4 + j] = m_loc[j];
        redl[tq][tk * 4 + j] = l_loc[j];
    }
    __syncthreads();
    if (t < 64) {
        float M = -__builtin_inff();
        #pragma unroll
        for (int p = 0; p < 16; ++p) M = fmaxf(M, redm[p][t]);
        float L = 0.0f;
        #pragma unroll
        for (int p = 0; p < 16; ++p) L += redl[p][t] * __expf(redm[p][t] - M);
        mg[(size_t)b * SEQ + k0 + t] = M;
        lg[(size_t)b * SEQ + k0 + t] = L;
    }
}

// ---------------------------------------------------------------------------
// Kernel 3: O[q,d] = sum_k exp(S[q,k]-m_k)/l_k * V[k,d]
// grid (64 qtiles, 4 b), 256 threads
// phase 1: (tq,tk) 4x4 S-tile -> P staged in LDS
// phase 2: (qo = t>>2, sub = t&3) owns q-row x 12 d cols
// ---------------------------------------------------------------------------
__global__ __launch_bounds__(256) void pv_kernel(
    const float* __restrict__ Q, const float* __restrict__ K,
    const float* __restrict__ V,
    const float* __restrict__ mg, const float* __restrict__ lg,
    float* __restrict__ out)
{
    __shared__ float Qt[48][68];
    __shared__ float Kt[48][68];
    __shared__ float Ps[64][68];
    __shared__ float Vs[64][52];
    __shared__ float smv[64];
    __shared__ float sil[64];

    const int t  = threadIdx.x;
    const int b  = blockIdx.y;
    const int q0 = blockIdx.x * 64;
    const int tq = t >> 4, tk = t & 15;
    const int qo = t >> 2, sub = t & 3;

    stage_T(Q + ((size_t)b * SEQ + q0) * HD, Qt, t);

    float o[12];
    #pragma unroll
    for (int w = 0; w < 12; ++w) o[w] = 0.0f;

    for (int kc = 0; kc < 64; ++kc) {
        __syncthreads();   // prev iter phase2 done; Qt staged (kc=0)
        stage_T(K + ((size_t)b * SEQ + kc * 64) * HD, Kt, t);
        #pragma unroll
        for (int i = 0; i < 3; ++i) {
            const int idx = i * 256 + t;
            const int row = idx / 12;
            const int seg = idx % 12;
            const float4 v = *reinterpret_cast<const float4*>(
                V + ((size_t)b * SEQ + kc * 64 + row) * HD + seg * 4);
            *reinterpret_cast<float4*>(&Vs[row][seg * 4]) = v;
        }
        if (t < 64) {
            smv[t] = mg[(size_t)b * SEQ + kc * 64 + t];
            sil[t] = 1.0f / lg[(size_t)b * SEQ + kc * 64 + t];
        }
        __syncthreads();

        // phase 1: S tile and P
        float acc[4][4];
        #pragma unroll
        for (int i = 0; i < 4; ++i)
            #pragma unroll
            for (int j = 0; j < 4; ++j) acc[i][j] = 0.0f;
        #pragma unroll
        for (int c = 0; c < 48; ++c) {
            const float4 qv = *reinterpret_cast<const float4*>(&Qt[c][tq * 4]);
            const float4 kv = *reinterpret_cast<const float4*>(&Kt[c][tk * 4]);
            const float qa[4] = {qv.x, qv.y, qv.z, qv.w};
            const float ka[4] = {kv.x, kv.y, kv.z, kv.w};
            #pragma unroll
            for (int i = 0; i < 4; ++i)
                #pragma unroll
                for (int j = 0; j < 4; ++j)
                    acc[i][j] = fmaf(qa[i], ka[j], acc[i][j]);
        }
        #pragma unroll
        for (int j = 0; j < 4; ++j) {
            const int kk = tk * 4 + j;
            const float mcol = smv[kk];
            const float il   = sil[kk];
            #pragma unroll
            for (int i = 0; i < 4; ++i) {
                Ps[tq * 4 + i][kk] = __expf(acc[i][j] * SCALE - mcol) * il;
            }
        }
        __syncthreads();

        // phase 2: O += P * V
        #pragma unroll
        for (int kk4 = 0; kk4 < 64; kk4 += 4) {
            const float4 p4 = *reinterpret_cast<const float4*>(&Ps[qo][kk4]);
            const float pa[4] = {p4.x, p4.y, p4.z, p4.w};
            #pragma unroll
            for (int jj = 0; jj < 4; ++jj) {
                const float p = pa[jj];
                const float* vrow = &Vs[kk4 + jj][sub * 12];
                const float4 v0 = *reinterpret_cast<const float4*>(vrow);
                const float4 v1 = *reinterpret_cast<const float4*>(vrow + 4);
                const float4 v2 = *reinterpret_cast<const float4*>(vrow + 8);
                o[0]  = fmaf(p, v0.x, o[0]);
                o[1]  = fmaf(p, v0.y, o[1]);
                o[2]  = fmaf(p, v0.z, o[2]);
                o[3]  = fmaf(p, v0.w, o[3]);
                o[4]  = fmaf(p, v1.x, o[4]);
                o[5]  = fmaf(p, v1.y, o[5]);
                o[6]  = fmaf(p, v1.z, o[6]);
                o[7]  = fmaf(p, v1.w, o[7]);
                o[8]  = fmaf(p, v2.x, o[8]);
                o[9]  = fmaf(p, v2.y, o[9]);
                o[10] = fmaf(p, v2.z, o[10]);
                o[11] = fmaf(p, v2.w, o[11]);
            }
        }
    }

    float* op = out + ((size_t)b * SEQ + q0 + qo) * HD + sub * 12;
    *reinterpret_cast<float4*>(op + 0) = make_float4(o[0], o[1], o[2], o[3]);
    *reinterpret_cast<float4*>(op + 4) = make_float4(o[4], o[5], o[6], o[7]);
    *reinterpret_cast<float4*>(op + 8) = make_float4(o[8], o[9], o[10], o[11]);
}

// ---------------------------------------------------------------------------
extern "C" void kernel_launch(void* const* d_in, const int* in_sizes, int n_in,
                              void* d_out, int out_size, void* d_ws, size_t ws_size,
                              hipStream_t stream)
{
    const float* x  = (const float*)d_in[0];
    const float* Wq = (const float*)d_in[1];
    const float* bq = (const float*)d_in[2];
    const float* Wk = (const float*)d_in[3];
    const float* bk = (const float*)d_in[4];
    const float* Wv = (const float*)d_in[5];
    const float* bv = (const float*)d_in[6];
    float* out = (float*)d_out;

    const size_t QSZ = (size_t)NB * SEQ * HD;     // 786432 floats
    float* Qb = (float*)d_ws;
    float* Kb = Qb + QSZ;
    float* Vb = Kb + QSZ;
    float* mg = Vb + QSZ;
    float* lg = mg + (size_t)NB * SEQ;

    proj_kernel<<<dim3((NB * SEQ) / 64), 256, 0, stream>>>(
        x, Wq, bq, Wk, bk, Wv, bv, Qb, Kb, Vb);
    stats_kernel<<<dim3(64, 4), 256, 0, stream>>>(Qb, Kb, mg, lg);
    pv_kernel<<<dim3(64, 4), 256, 0, stream>>>(Qb, Kb, Vb, mg, lg, out);
}

// Round 3
// 374.971 us; speedup vs baseline: 1.8451x; 1.8451x over previous
//
#include <hip/hip_runtime.h>
#include <hip/hip_bf16.h>

#define NB 4
#define SEQ 4096
#define CDIM 768
#define HD 48
#define DP 64

typedef __attribute__((ext_vector_type(8))) __bf16 bf16x8;
typedef __attribute__((ext_vector_type(16))) float f32x16;

// (1/sqrt(48)) * log2(e): folded into Q at projection time so P = exp2(S_acc)
static constexpr float SCALE_LOG2E = 0.20823542135164923f;

__device__ __forceinline__ bf16x8 ldg8(const __hip_bfloat16* p) {
    uint4 u = *reinterpret_cast<const uint4*>(p);
    bf16x8 r;
    __builtin_memcpy(&r, &u, 16);
    return r;
}
__device__ __forceinline__ unsigned pk2(float lo, float hi) {
    const __hip_bfloat16 a = __float2bfloat16(lo);
    const __hip_bfloat16 b = __float2bfloat16(hi);
    unsigned short ua, ub;
    __builtin_memcpy(&ua, &a, 2);
    __builtin_memcpy(&ub, &b, 2);
    return (unsigned)ua | ((unsigned)ub << 16);
}
__device__ __forceinline__ bf16x8 mk8(unsigned w0, unsigned w1, unsigned w2, unsigned w3) {
    const uint4 u = make_uint4(w0, w1, w2, w3);
    bf16x8 r;
    __builtin_memcpy(&r, &u, 16);
    return r;
}

// ---------------------------------------------------------------------------
// Kernel 1: projections (fp32 VALU, from R1).  Writes:
//   Qp bf16 [B][S][64]  = (x@Wq + bq) * SCALE_LOG2E, cols 48..63 zero
//   Kp bf16 [B][S][64]  = (x@Wk + bk), cols 48..63 zero
//   Vf fp32 [B][S][48]  = (x@Wv + bv)
// ---------------------------------------------------------------------------
__global__ __launch_bounds__(256) void proj_kernel(
    const float* __restrict__ x,
    const float* __restrict__ Wq, const float* __restrict__ bq,
    const float* __restrict__ Wk, const float* __restrict__ bk,
    const float* __restrict__ Wv, const float* __restrict__ bv,
    __hip_bfloat16* __restrict__ Qp, __hip_bfloat16* __restrict__ Kp,
    float* __restrict__ Vf)
{
    __shared__ float xst[16][68];
    __shared__ float wsm[16][146];

    const int t  = threadIdx.x;
    const int tr = t >> 4;
    const int tc = t & 15;
    const int r0 = blockIdx.x * 64;

    float acc[4][9];
    #pragma unroll
    for (int i = 0; i < 4; ++i)
        #pragma unroll
        for (int u = 0; u < 9; ++u) acc[i][u] = 0.0f;

    for (int kc = 0; kc < 48; ++kc) {
        {
            const int row = t >> 2;
            const int cq  = (t & 3) * 4;
            const float4 xv = *reinterpret_cast<const float4*>(
                &x[(size_t)(r0 + row) * CDIM + kc * 16 + cq]);
            xst[cq + 0][row] = xv.x;
            xst[cq + 1][row] = xv.y;
            xst[cq + 2][row] = xv.z;
            xst[cq + 3][row] = xv.w;
        }
        #pragma unroll
        for (int u = 0; u < 9; ++u) {
            const int idx = u * 256 + t;
            const int c = idx / 144;
            const int j = idx % 144;
            const int gr = kc * 16 + c;
            float w;
            if (j < 48)       w = Wq[gr * 48 + j];
            else if (j < 96)  w = Wk[gr * 48 + (j - 48)];
            else              w = Wv[gr * 48 + (j - 96)];
            wsm[c][j] = w;
        }
        __syncthreads();
        #pragma unroll
        for (int c = 0; c < 16; ++c) {
            const float4 xv = *reinterpret_cast<const float4*>(&xst[c][tr * 4]);
            float wv[9];
            #pragma unroll
            for (int u = 0; u < 9; ++u) wv[u] = wsm[c][tc * 9 + u];
            #pragma unroll
            for (int u = 0; u < 9; ++u) {
                acc[0][u] = fmaf(xv.x, wv[u], acc[0][u]);
                acc[1][u] = fmaf(xv.y, wv[u], acc[1][u]);
                acc[2][u] = fmaf(xv.z, wv[u], acc[2][u]);
                acc[3][u] = fmaf(xv.w, wv[u], acc[3][u]);
            }
        }
        __syncthreads();
    }
    #pragma unroll
    for (int u = 0; u < 9; ++u) {
        const int j   = tc * 9 + u;
        const int mat = j / 48;
        const int jj  = j % 48;
        const float bias = (mat == 0 ? bq : (mat == 1 ? bk : bv))[jj];
        #pragma unroll
        for (int i = 0; i < 4; ++i) {
            const int row = r0 + tr * 4 + i;
            const float val = acc[i][u] + bias;
            if (mat == 0)
                Qp[(size_t)row * DP + jj] = __float2bfloat16(val * SCALE_LOG2E);
            else if (mat == 1)
                Kp[(size_t)row * DP + jj] = __float2bfloat16(val);
            else
                Vf[(size_t)row * HD + jj] = val;
        }
    }
    // zero-pad channels 48..63 of Qp, Kp (these enter the MFMA K-dim sums)
    {
        const int row = r0 + (t >> 2);
        const int c0  = 48 + (t & 3) * 4;
        *reinterpret_cast<uint2*>(&Qp[(size_t)row * DP + c0]) = make_uint2(0u, 0u);
        *reinterpret_cast<uint2*>(&Kp[(size_t)row * DP + c0]) = make_uint2(0u, 0u);
    }
}

// ---------------------------------------------------------------------------
// Kernel 2: per-column softmax denominator + V fold.
// 1 wave per 32-k strip.  S^T tile = mfma(K-rows, Q^T); l_k = sum_q exp2.
// Then Vt[b][d][k] = bf16( Vf[k][d] / l_k ), d rows 48..63 zeroed.
// ---------------------------------------------------------------------------
__global__ __launch_bounds__(64) void stats_kernel(
    const __hip_bfloat16* __restrict__ Qp, const __hip_bfloat16* __restrict__ Kp,
    const float* __restrict__ Vf, __hip_bfloat16* __restrict__ Vt)
{
    __shared__ float fsh[32];
    const int l   = threadIdx.x;
    const int lo5 = l & 31, hi = l >> 5;
    const int b   = blockIdx.y;
    const int k0  = blockIdx.x * 32;

    bf16x8 ka[4];
    const __hip_bfloat16* kb = Kp + ((size_t)(b * SEQ) + k0 + lo5) * DP + hi * 8;
    #pragma unroll
    for (int s = 0; s < 4; ++s) ka[s] = ldg8(kb + 16 * s);

    float lsum[16];
    #pragma unroll
    for (int r = 0; r < 16; ++r) lsum[r] = 0.0f;

    const __hip_bfloat16* qbase = Qp + (size_t)(b * SEQ) * DP + hi * 8;
    #pragma unroll 2
    for (int q0 = 0; q0 < SEQ; q0 += 32) {
        bf16x8 qb[4];
        #pragma unroll
        for (int s = 0; s < 4; ++s)
            qb[s] = ldg8(qbase + (size_t)(q0 + lo5) * DP + 16 * s);
        f32x16 acc = {};
        #pragma unroll
        for (int s = 0; s < 4; ++s)
            acc = __builtin_amdgcn_mfma_f32_32x32x16_bf16(ka[s], qb[s], acc, 0, 0, 0);
        #pragma unroll
        for (int r = 0; r < 16; ++r) lsum[r] += __builtin_amdgcn_exp2f(acc[r]);
    }

    // reduce across the 32 lanes sharing each half (columns of S^T)
    #pragma unroll
    for (int r = 0; r < 16; ++r) {
        lsum[r] += __shfl_xor(lsum[r], 1);
        lsum[r] += __shfl_xor(lsum[r], 2);
        lsum[r] += __shfl_xor(lsum[r], 4);
        lsum[r] += __shfl_xor(lsum[r], 8);
        lsum[r] += __shfl_xor(lsum[r], 16);
    }
    if (lo5 == 0) {
        #pragma unroll
        for (int r = 0; r < 16; ++r) {
            const int row = (r & 3) + 8 * (r >> 2) + 4 * hi;   // C/D row map
            fsh[row] = 1.0f / lsum[r];
        }
    }
    __syncthreads();

    // scale V by 1/l and write transposed: Vt[b][d][k]
    const int kp = l & 15;      // k-pair
    const int dg = l >> 4;      // 0..3
    const int kk = k0 + 2 * kp;
    const float f0 = fsh[2 * kp], f1 = fsh[2 * kp + 1];
    #pragma unroll
    for (int dd = 0; dd < 12; ++dd) {
        const int d = dg * 12 + dd;
        const float v0 = Vf[(size_t)(b * SEQ + kk) * HD + d];
        const float v1 = Vf[(size_t)(b * SEQ + kk + 1) * HD + d];
        *reinterpret_cast<unsigned*>(&Vt[((size_t)b * DP + d) * SEQ + kk]) =
            pk2(v0 * f0, v1 * f1);
    }
    #pragma unroll
    for (int dd = 0; dd < 4; ++dd) {
        const int d = 48 + dg * 4 + dd;
        *reinterpret_cast<unsigned*>(&Vt[((size_t)b * DP + d) * SEQ + kk]) = 0u;
    }
}

// ---------------------------------------------------------------------------
// Kernel 3: O[q,d] = sum_k exp2(S^[q,k]) * Vt[d,k].
// 1 wave per 32-q strip.  Swapped QK^T (mfma(K,Q)) -> P lane-local in q;
// in-register P->bf16 A-frag assembly via cvt_pk + half-swap (shfl_xor 32).
// ---------------------------------------------------------------------------
__global__ __launch_bounds__(64) void pv_kernel(
    const __hip_bfloat16* __restrict__ Qp, const __hip_bfloat16* __restrict__ Kp,
    const __hip_bfloat16* __restrict__ Vt, float* __restrict__ out)
{
    const int l   = threadIdx.x;
    const int lo5 = l & 31, hi = l >> 5;
    const int b   = blockIdx.y;
    const int q0  = blockIdx.x * 32;

    bf16x8 qb[4];
    const __hip_bfloat16* qbp = Qp + ((size_t)(b * SEQ) + q0 + lo5) * DP + hi * 8;
    #pragma unroll
    for (int s = 0; s < 4; ++s) qb[s] = ldg8(qbp + 16 * s);

    f32x16 o0 = {}, o1 = {};
    const __hip_bfloat16* kbase = Kp + (size_t)(b * SEQ) * DP + hi * 8;
    const __hip_bfloat16* vbase = Vt + (size_t)(b * DP) * SEQ + hi * 8;
    const bool islo = (hi == 0);

    #pragma unroll 2
    for (int k0 = 0; k0 < SEQ; k0 += 32) {
        bf16x8 ka[4];
        #pragma unroll
        for (int s = 0; s < 4; ++s)
            ka[s] = ldg8(kbase + (size_t)(k0 + lo5) * DP + 16 * s);
        f32x16 acc = {};
        #pragma unroll
        for (int s = 0; s < 4; ++s)
            acc = __builtin_amdgcn_mfma_f32_32x32x16_bf16(ka[s], qb[s], acc, 0, 0, 0);

        float p[16];
        #pragma unroll
        for (int r = 0; r < 16; ++r) p[r] = __builtin_amdgcn_exp2f(acc[r]);

        // pack row-pairs: x* = rows (0,1),(2,3) of each 8-row group (lo half),
        // y* = rows (8,9),(10,11)... (hi half); swap halves across lane 32.
        const unsigned x0 = pk2(p[0],  p[1]),  x1 = pk2(p[2],  p[3]);
        const unsigned y0 = pk2(p[4],  p[5]),  y1 = pk2(p[6],  p[7]);
        const unsigned x2 = pk2(p[8],  p[9]),  x3 = pk2(p[10], p[11]);
        const unsigned y2 = pk2(p[12], p[13]), y3 = pk2(p[14], p[15]);

        unsigned w0, w1, w2, w3, w4, w5, w6, w7;
        { const unsigned ax = __shfl_xor(x0, 32), bx = __shfl_xor(y0, 32);
          w0 = islo ? x0 : bx;  w2 = islo ? ax : y0; }
        { const unsigned ax = __shfl_xor(x1, 32), bx = __shfl_xor(y1, 32);
          w1 = islo ? x1 : bx;  w3 = islo ? ax : y1; }
        { const unsigned ax = __shfl_xor(x2, 32), bx = __shfl_xor(y2, 32);
          w4 = islo ? x2 : bx;  w6 = islo ? ax : y2; }
        { const unsigned ax = __shfl_xor(x3, 32), bx = __shfl_xor(y3, 32);
          w5 = islo ? x3 : bx;  w7 = islo ? ax : y3; }

        const bf16x8 pa0 = mk8(w0, w1, w2, w3);
        const bf16x8 pa1 = mk8(w4, w5, w6, w7);

        const __hip_bfloat16* v0p = vbase + (size_t)lo5 * SEQ + k0;
        const __hip_bfloat16* v1p = vbase + (size_t)(32 + lo5) * SEQ + k0;
        const bf16x8 va = ldg8(v0p), vb2 = ldg8(v0p + 16);
        const bf16x8 vc = ldg8(v1p), vd  = ldg8(v1p + 16);
        o0 = __builtin_amdgcn_mfma_f32_32x32x16_bf16(pa0, va,  o0, 0, 0, 0);
        o0 = __builtin_amdgcn_mfma_f32_32x32x16_bf16(pa1, vb2, o0, 0, 0, 0);
        o1 = __builtin_amdgcn_mfma_f32_32x32x16_bf16(pa0, vc,  o1, 0, 0, 0);
        o1 = __builtin_amdgcn_mfma_f32_32x32x16_bf16(pa1, vd,  o1, 0, 0, 0);
    }

    #pragma unroll
    for (int r = 0; r < 16; ++r) {
        const int q = q0 + (r & 3) + 8 * (r >> 2) + 4 * hi;
        out[((size_t)(b * SEQ) + q) * HD + lo5] = o0[r];
        if (lo5 < 16)
            out[((size_t)(b * SEQ) + q) * HD + 32 + lo5] = o1[r];
    }
}

// ---------------------------------------------------------------------------
extern "C" void kernel_launch(void* const* d_in, const int* in_sizes, int n_in,
                              void* d_out, int out_size, void* d_ws, size_t ws_size,
                              hipStream_t stream)
{
    const float* x  = (const float*)d_in[0];
    const float* Wq = (const float*)d_in[1];
    const float* bq = (const float*)d_in[2];
    const float* Wk = (const float*)d_in[3];
    const float* bk = (const float*)d_in[4];
    const float* Wv = (const float*)d_in[5];
    const float* bv = (const float*)d_in[6];
    float* out = (float*)d_out;

    __hip_bfloat16* Qp = (__hip_bfloat16*)d_ws;                     // 2 MB
    __hip_bfloat16* Kp = Qp + (size_t)NB * SEQ * DP;                // 2 MB
    float*          Vf = (float*)(Kp + (size_t)NB * SEQ * DP);      // 3 MB
    __hip_bfloat16* Vt = (__hip_bfloat16*)(Vf + (size_t)NB * SEQ * HD); // 2 MB

    proj_kernel<<<dim3((NB * SEQ) / 64), 256, 0, stream>>>(
        x, Wq, bq, Wk, bk, Wv, bv, Qp, Kp, Vf);
    stats_kernel<<<dim3(SEQ / 32, NB), 64, 0, stream>>>(Qp, Kp, Vf, Vt);
    pv_kernel<<<dim3(SEQ / 32, NB), 64, 0, stream>>>(Qp, Kp, Vt, out);
}

// Round 4
// 154.132 us; speedup vs baseline: 4.4888x; 2.4328x over previous
//
#include <hip/hip_runtime.h>
#include <hip/hip_bf16.h>

#define NB 4
#define SEQ 4096
#define CDIM 768
#define HD 48
#define DP 64

typedef __attribute__((ext_vector_type(8))) __bf16 bf16x8;
typedef __attribute__((ext_vector_type(16))) float f32x16;

// (1/sqrt(48)) * log2(e): folded into Q at projection store so P = exp2(S_acc)
static constexpr float SCALE_LOG2E = 0.20823542135164923f;

__device__ __forceinline__ bf16x8 ldg8(const __hip_bfloat16* p) {
    uint4 u = *reinterpret_cast<const uint4*>(p);
    bf16x8 r;
    __builtin_memcpy(&r, &u, 16);
    return r;
}
__device__ __forceinline__ unsigned pk2(float lo, float hi) {
    const __hip_bfloat16 a = __float2bfloat16(lo);
    const __hip_bfloat16 b = __float2bfloat16(hi);
    unsigned short ua, ub;
    __builtin_memcpy(&ua, &a, 2);
    __builtin_memcpy(&ub, &b, 2);
    return (unsigned)ua | ((unsigned)ub << 16);
}
__device__ __forceinline__ bf16x8 mk8(unsigned w0, unsigned w1, unsigned w2, unsigned w3) {
    const uint4 u = make_uint4(w0, w1, w2, w3);
    bf16x8 r;
    __builtin_memcpy(&r, &u, 16);
    return r;
}
// split 8 fp32 into hi/lo bf16x8 (x ~= hi + lo, ~2^-17 rel precision)
__device__ __forceinline__ void cvt_hilo8(const float* f, bf16x8& xh, bf16x8& xl) {
    unsigned uh[4], ul[4];
    #pragma unroll
    for (int i = 0; i < 4; ++i) {
        const float a = f[2 * i], b = f[2 * i + 1];
        const __hip_bfloat16 ha = __float2bfloat16(a);
        const __hip_bfloat16 hb = __float2bfloat16(b);
        const float la = a - __bfloat162float(ha);
        const float lb = b - __bfloat162float(hb);
        unsigned short ua, ub;
        __builtin_memcpy(&ua, &ha, 2);
        __builtin_memcpy(&ub, &hb, 2);
        uh[i] = (unsigned)ua | ((unsigned)ub << 16);
        ul[i] = pk2(la, lb);
    }
    const uint4 vh = make_uint4(uh[0], uh[1], uh[2], uh[3]);
    const uint4 vl = make_uint4(ul[0], ul[1], ul[2], ul[3]);
    __builtin_memcpy(&xh, &vh, 16);
    __builtin_memcpy(&xl, &vl, 16);
}

// ---------------------------------------------------------------------------
// Kernel 0: prep — build W transposed+split:  Wth/Wtl [160][768] bf16
//   cols 0..47 = Wq, 48..95 = Wk, 96..143 = Wv, 144..159 = zero; bias[160].
// ---------------------------------------------------------------------------
__global__ __launch_bounds__(256) void prep_kernel(
    const float* __restrict__ Wq, const float* __restrict__ Wk,
    const float* __restrict__ Wv,
    const float* __restrict__ bq, const float* __restrict__ bk,
    const float* __restrict__ bv,
    __hip_bfloat16* __restrict__ Wth, __hip_bfloat16* __restrict__ Wtl,
    float* __restrict__ bias)
{
    const int idx = blockIdx.x * 256 + threadIdx.x;
    if (idx < 160 * 96) {
        const int n  = idx / 96;
        const int k0 = (idx % 96) * 8;
        const float* src = (n < 48) ? Wq : (n < 96) ? Wk : (n < 144) ? Wv : nullptr;
        const int col = (n < 48) ? n : (n < 96) ? (n - 48) : (n - 96);
        #pragma unroll
        for (int j = 0; j < 8; ++j) {
            const float wv = src ? src[(size_t)(k0 + j) * HD + col] : 0.0f;
            const __hip_bfloat16 h = __float2bfloat16(wv);
            const float lo = wv - __bfloat162float(h);
            Wth[(size_t)n * CDIM + k0 + j] = h;
            Wtl[(size_t)n * CDIM + k0 + j] = __float2bfloat16(lo);
        }
    }
    if (blockIdx.x == 0 && threadIdx.x < 160) {
        const int t = threadIdx.x;
        bias[t] = (t < 48) ? bq[t] : (t < 96) ? bk[t - 48] : (t < 144) ? bv[t - 96] : 0.0f;
    }
}

// ---------------------------------------------------------------------------
// Kernel 1: proj via split-bf16 MFMA.
// grid (128 rowgroups, 5 coltiles) x 256 thr; wave w -> row-tile (bx*4+w)*32.
// Writes Qp bf16 [B*S][64] (scaled), Kp bf16 [B*S][64], Vf fp32 [B*S][48].
// ---------------------------------------------------------------------------
__global__ __launch_bounds__(256) void proj_kernel(
    const float* __restrict__ x,
    const __hip_bfloat16* __restrict__ Wth, const __hip_bfloat16* __restrict__ Wtl,
    const float* __restrict__ bias,
    __hip_bfloat16* __restrict__ Qp, __hip_bfloat16* __restrict__ Kp,
    float* __restrict__ Vf)
{
    const int t   = threadIdx.x;
    const int w   = t >> 6;
    const int l   = t & 63;
    const int lo5 = l & 31, h = l >> 5;
    const int m0  = (blockIdx.x * 4 + w) * 32;
    const int n_g = blockIdx.y * 32 + lo5;

    const float* xrow = x + (size_t)(m0 + lo5) * CDIM + 8 * h;
    const __hip_bfloat16* whp = Wth + (size_t)n_g * CDIM + 8 * h;
    const __hip_bfloat16* wlp = Wtl + (size_t)n_g * CDIM + 8 * h;

    f32x16 acc = {};
    #pragma unroll 4
    for (int k0 = 0; k0 < CDIM; k0 += 16) {
        const float4 xa = *reinterpret_cast<const float4*>(xrow + k0);
        const float4 xb = *reinterpret_cast<const float4*>(xrow + k0 + 4);
        const float f[8] = {xa.x, xa.y, xa.z, xa.w, xb.x, xb.y, xb.z, xb.w};
        bf16x8 xh, xl;
        cvt_hilo8(f, xh, xl);
        const bf16x8 bh = ldg8(whp + k0);
        const bf16x8 bl = ldg8(wlp + k0);
        acc = __builtin_amdgcn_mfma_f32_32x32x16_bf16(xh, bh, acc, 0, 0, 0);
        acc = __builtin_amdgcn_mfma_f32_32x32x16_bf16(xh, bl, acc, 0, 0, 0);
        acc = __builtin_amdgcn_mfma_f32_32x32x16_bf16(xl, bh, acc, 0, 0, 0);
    }

    const float bs = bias[n_g];
    #pragma unroll
    for (int r = 0; r < 16; ++r) {
        const int m = m0 + (r & 3) + 8 * (r >> 2) + 4 * h;
        const float val = acc[r] + bs;
        if (n_g < 48)
            Qp[(size_t)m * DP + n_g] = __float2bfloat16(val * SCALE_LOG2E);
        else if (n_g < 96)
            Kp[(size_t)m * DP + (n_g - 48)] = __float2bfloat16(val);
        else if (n_g < 144)
            Vf[(size_t)m * HD + (n_g - 96)] = val;
    }
}

// ---------------------------------------------------------------------------
// Kernel 2: per-column softmax denominator + V fold.  4 waves split q-range.
// l_k = sum_q exp2(Shat[q,k]);  Vt[b][d][k] = bf16(Vf[k][d]/l_k), d 48..63 = 0
// ---------------------------------------------------------------------------
__global__ __launch_bounds__(256) void stats_kernel(
    const __hip_bfloat16* __restrict__ Qp, const __hip_bfloat16* __restrict__ Kp,
    const float* __restrict__ Vf, __hip_bfloat16* __restrict__ Vt)
{
    __shared__ float part[4][32];
    __shared__ float linv[32];

    const int t   = threadIdx.x;
    const int w   = t >> 6;
    const int l   = t & 63;
    const int lo5 = l & 31, h = l >> 5;
    const int b   = blockIdx.y;
    const int k0  = blockIdx.x * 32;

    bf16x8 ka[3];
    const __hip_bfloat16* kb = Kp + ((size_t)(b * SEQ) + k0 + lo5) * DP + 8 * h;
    #pragma unroll
    for (int s = 0; s < 3; ++s) ka[s] = ldg8(kb + 16 * s);

    float lsum[16];
    #pragma unroll
    for (int r = 0; r < 16; ++r) lsum[r] = 0.0f;

    const __hip_bfloat16* qbase =
        Qp + ((size_t)(b * SEQ) + w * (SEQ / 4)) * DP + 8 * h;
    #pragma unroll 2
    for (int qq = 0; qq < SEQ / 4; qq += 32) {
        bf16x8 qb[3];
        #pragma unroll
        for (int s = 0; s < 3; ++s)
            qb[s] = ldg8(qbase + (size_t)(qq + lo5) * DP + 16 * s);
        f32x16 acc = {};
        #pragma unroll
        for (int s = 0; s < 3; ++s)
            acc = __builtin_amdgcn_mfma_f32_32x32x16_bf16(ka[s], qb[s], acc, 0, 0, 0);
        #pragma unroll
        for (int r = 0; r < 16; ++r) lsum[r] += __builtin_amdgcn_exp2f(acc[r]);
    }

    #pragma unroll
    for (int r = 0; r < 16; ++r) {
        lsum[r] += __shfl_xor(lsum[r], 1);
        lsum[r] += __shfl_xor(lsum[r], 2);
        lsum[r] += __shfl_xor(lsum[r], 4);
        lsum[r] += __shfl_xor(lsum[r], 8);
        lsum[r] += __shfl_xor(lsum[r], 16);
    }
    if (lo5 == 0) {
        #pragma unroll
        for (int r = 0; r < 16; ++r)
            part[w][(r & 3) + 8 * (r >> 2) + 4 * h] = lsum[r];
    }
    __syncthreads();
    if (t < 32)
        linv[t] = 1.0f / (part[0][t] + part[1][t] + part[2][t] + part[3][t]);
    __syncthreads();

    // V fold across all 256 threads: kp = k-pair, dg -> 3 d's each
    const int kp = t & 15;
    const int dg = t >> 4;
    const int kk = k0 + 2 * kp;
    const float f0 = linv[2 * kp], f1 = linv[2 * kp + 1];
    #pragma unroll
    for (int dd = 0; dd < 3; ++dd) {
        const int d = dg * 3 + dd;
        const float v0 = Vf[(size_t)(b * SEQ + kk) * HD + d];
        const float v1 = Vf[(size_t)(b * SEQ + kk + 1) * HD + d];
        *reinterpret_cast<unsigned*>(&Vt[((size_t)b * DP + d) * SEQ + kk]) =
            pk2(v0 * f0, v1 * f1);
    }
    *reinterpret_cast<unsigned*>(&Vt[((size_t)b * DP + 48 + dg) * SEQ + kk]) = 0u;
}

// ---------------------------------------------------------------------------
// Kernel 3: O[q,d] = sum_k exp2(Shat[q,k]) * Vt[d,k].  4 waves split k-range,
// LDS-reduce the O accumulators; wave 0 writes.
// ---------------------------------------------------------------------------
__global__ __launch_bounds__(256) void pv_kernel(
    const __hip_bfloat16* __restrict__ Qp, const __hip_bfloat16* __restrict__ Kp,
    const __hip_bfloat16* __restrict__ Vt, float* __restrict__ out)
{
    __shared__ float red[3][32][64];

    const int t   = threadIdx.x;
    const int w   = t >> 6;
    const int l   = t & 63;
    const int lo5 = l & 31, h = l >> 5;
    const int b   = blockIdx.y;
    const int q0  = blockIdx.x * 32;
    const bool islo = (h == 0);

    bf16x8 qb[3];
    const __hip_bfloat16* qbp = Qp + ((size_t)(b * SEQ) + q0 + lo5) * DP + 8 * h;
    #pragma unroll
    for (int s = 0; s < 3; ++s) qb[s] = ldg8(qbp + 16 * s);

    f32x16 o0 = {}, o1 = {};
    const __hip_bfloat16* kbase =
        Kp + ((size_t)(b * SEQ) + w * (SEQ / 4)) * DP + 8 * h;
    const __hip_bfloat16* vbase =
        Vt + (size_t)(b * DP) * SEQ + w * (SEQ / 4) + 8 * h;

    #pragma unroll 2
    for (int kk = 0; kk < SEQ / 4; kk += 32) {
        bf16x8 ka[3];
        #pragma unroll
        for (int s = 0; s < 3; ++s)
            ka[s] = ldg8(kbase + (size_t)(kk + lo5) * DP + 16 * s);
        f32x16 acc = {};
        #pragma unroll
        for (int s = 0; s < 3; ++s)
            acc = __builtin_amdgcn_mfma_f32_32x32x16_bf16(ka[s], qb[s], acc, 0, 0, 0);

        float p[16];
        #pragma unroll
        for (int r = 0; r < 16; ++r) p[r] = __builtin_amdgcn_exp2f(acc[r]);

        const unsigned x0 = pk2(p[0],  p[1]),  x1 = pk2(p[2],  p[3]);
        const unsigned y0 = pk2(p[4],  p[5]),  y1 = pk2(p[6],  p[7]);
        const unsigned x2 = pk2(p[8],  p[9]),  x3 = pk2(p[10], p[11]);
        const unsigned y2 = pk2(p[12], p[13]), y3 = pk2(p[14], p[15]);

        unsigned w0, w1, w2, w3, w4, w5, w6, w7;
        { const unsigned ax = __shfl_xor(x0, 32), bx = __shfl_xor(y0, 32);
          w0 = islo ? x0 : bx;  w2 = islo ? ax : y0; }
        { const unsigned ax = __shfl_xor(x1, 32), bx = __shfl_xor(y1, 32);
          w1 = islo ? x1 : bx;  w3 = islo ? ax : y1; }
        { const unsigned ax = __shfl_xor(x2, 32), bx = __shfl_xor(y2, 32);
          w4 = islo ? x2 : bx;  w6 = islo ? ax : y2; }
        { const unsigned ax = __shfl_xor(x3, 32), bx = __shfl_xor(y3, 32);
          w5 = islo ? x3 : bx;  w7 = islo ? ax : y3; }

        const bf16x8 pa0 = mk8(w0, w1, w2, w3);
        const bf16x8 pa1 = mk8(w4, w5, w6, w7);

        const __hip_bfloat16* v0p = vbase + (size_t)lo5 * SEQ + kk;
        const __hip_bfloat16* v1p = vbase + (size_t)(32 + lo5) * SEQ + kk;
        const bf16x8 va = ldg8(v0p), vb2 = ldg8(v0p + 16);
        const bf16x8 vc = ldg8(v1p), vd  = ldg8(v1p + 16);
        o0 = __builtin_amdgcn_mfma_f32_32x32x16_bf16(pa0, va,  o0, 0, 0, 0);
        o0 = __builtin_amdgcn_mfma_f32_32x32x16_bf16(pa1, vb2, o0, 0, 0, 0);
        o1 = __builtin_amdgcn_mfma_f32_32x32x16_bf16(pa0, vc,  o1, 0, 0, 0);
        o1 = __builtin_amdgcn_mfma_f32_32x32x16_bf16(pa1, vd,  o1, 0, 0, 0);
    }

    if (w > 0) {
        #pragma unroll
        for (int r = 0; r < 16; ++r) {
            red[w - 1][r][l]      = o0[r];
            red[w - 1][16 + r][l] = o1[r];
        }
    }
    __syncthreads();
    if (w == 0) {
        #pragma unroll
        for (int r = 0; r < 16; ++r) {
            o0[r] += red[0][r][l] + red[1][r][l] + red[2][r][l];
            o1[r] += red[0][16 + r][l] + red[1][16 + r][l] + red[2][16 + r][l];
        }
        #pragma unroll
        for (int r = 0; r < 16; ++r) {
            const int q = q0 + (r & 3) + 8 * (r >> 2) + 4 * h;
            out[((size_t)(b * SEQ) + q) * HD + lo5] = o0[r];
            if (lo5 < 16)
                out[((size_t)(b * SEQ) + q) * HD + 32 + lo5] = o1[r];
        }
    }
}

// ---------------------------------------------------------------------------
extern "C" void kernel_launch(void* const* d_in, const int* in_sizes, int n_in,
                              void* d_out, int out_size, void* d_ws, size_t ws_size,
                              hipStream_t stream)
{
    const float* x  = (const float*)d_in[0];
    const float* Wq = (const float*)d_in[1];
    const float* bq = (const float*)d_in[2];
    const float* Wk = (const float*)d_in[3];
    const float* bk = (const float*)d_in[4];
    const float* Wv = (const float*)d_in[5];
    const float* bv = (const float*)d_in[6];
    float* out = (float*)d_out;

    __hip_bfloat16* Qp  = (__hip_bfloat16*)d_ws;                         // 2 MB
    __hip_bfloat16* Kp  = Qp + (size_t)NB * SEQ * DP;                    // 2 MB
    float*          Vf  = (float*)(Kp + (size_t)NB * SEQ * DP);          // 3 MB
    __hip_bfloat16* Vt  = (__hip_bfloat16*)(Vf + (size_t)NB * SEQ * HD); // 2 MB
    __hip_bfloat16* Wth = Vt + (size_t)NB * DP * SEQ;                    // 240 KB
    __hip_bfloat16* Wtl = Wth + (size_t)160 * CDIM;                      // 240 KB
    float*          bias = (float*)(Wtl + (size_t)160 * CDIM);           // 640 B

    prep_kernel<<<dim3(60), 256, 0, stream>>>(Wq, Wk, Wv, bq, bk, bv, Wth, Wtl, bias);
    proj_kernel<<<dim3(128, 5), 256, 0, stream>>>(x, Wth, Wtl, bias, Qp, Kp, Vf);
    stats_kernel<<<dim3(SEQ / 32, NB), 256, 0, stream>>>(Qp, Kp, Vf, Vt);
    pv_kernel<<<dim3(SEQ / 32, NB), 256, 0, stream>>>(Qp, Kp, Vt, out);
}

// Round 5
// 102.458 us; speedup vs baseline: 6.7527x; 1.5043x over previous
//
#include <hip/hip_runtime.h>
#include <hip/hip_bf16.h>

#define NB 4
#define SEQ 4096
#define CDIM 768
#define HD 48

typedef __attribute__((ext_vector_type(8))) __bf16 bf16x8;
typedef __attribute__((ext_vector_type(16))) float f32x16;

// (1/sqrt(48)) * log2(e): folded into Q at projection store so P = exp2(S_acc)
static constexpr float SCALE_LOG2E = 0.20823542135164923f;

__device__ __forceinline__ bf16x8 ldg8(const __hip_bfloat16* p) {
    uint4 u = *reinterpret_cast<const uint4*>(p);
    bf16x8 r;
    __builtin_memcpy(&r, &u, 16);
    return r;
}
__device__ __forceinline__ unsigned pk2(float lo, float hi) {
    const __hip_bfloat16 a = __float2bfloat16(lo);
    const __hip_bfloat16 b = __float2bfloat16(hi);
    unsigned short ua, ub;
    __builtin_memcpy(&ua, &a, 2);
    __builtin_memcpy(&ub, &b, 2);
    return (unsigned)ua | ((unsigned)ub << 16);
}
__device__ __forceinline__ bf16x8 mk8(unsigned w0, unsigned w1, unsigned w2, unsigned w3) {
    const uint4 u = make_uint4(w0, w1, w2, w3);
    bf16x8 r;
    __builtin_memcpy(&r, &u, 16);
    return r;
}
__device__ __forceinline__ bf16x8 cvt8(const float* f) {
    const uint4 u = make_uint4(pk2(f[0], f[1]), pk2(f[2], f[3]),
                               pk2(f[4], f[5]), pk2(f[6], f[7]));
    bf16x8 r;
    __builtin_memcpy(&r, &u, 16);
    return r;
}
// fragment base offset (elements): frag (tile, s, h) is 256 contiguous bf16
__device__ __forceinline__ size_t fragOff(int tile, int s, int h) {
    return (((size_t)tile * 3 + s) * 2 + h) * 256;
}

// ---------------------------------------------------------------------------
// Kernel 0: prep — W transposed: Wth [160][768] bf16 (48 q | 48 k | 48 v | 16 z)
// ---------------------------------------------------------------------------
__global__ __launch_bounds__(256) void prep_kernel(
    const float* __restrict__ Wq, const float* __restrict__ Wk,
    const float* __restrict__ Wv,
    const float* __restrict__ bq, const float* __restrict__ bk,
    const float* __restrict__ bv,
    __hip_bfloat16* __restrict__ Wth, float* __restrict__ bias)
{
    const int idx = blockIdx.x * 256 + threadIdx.x;
    if (idx < 160 * 96) {
        const int n  = idx / 96;
        const int k0 = (idx % 96) * 8;
        const float* src = (n < 48) ? Wq : (n < 96) ? Wk : (n < 144) ? Wv : nullptr;
        const int col = (n < 48) ? n : (n < 96) ? (n - 48) : (n - 96);
        #pragma unroll
        for (int j = 0; j < 8; ++j) {
            const float wv = src ? src[(size_t)(k0 + j) * HD + col] : 0.0f;
            Wth[(size_t)n * CDIM + k0 + j] = __float2bfloat16(wv);
        }
    }
    if (blockIdx.x == 0 && threadIdx.x < 160) {
        const int t = threadIdx.x;
        bias[t] = (t < 48) ? bq[t] : (t < 96) ? bk[t - 48] : (t < 144) ? bv[t - 96] : 0.0f;
    }
}

// ---------------------------------------------------------------------------
// Kernel 1: proj, plain bf16 MFMA.  grid (128 rowgroups, 5 coltiles) x 4 waves.
// Writes Qf/Kf in MFMA-fragment-major layout, Vf fp32 row-major.
// ---------------------------------------------------------------------------
__global__ __launch_bounds__(256) void proj_kernel(
    const float* __restrict__ x,
    const __hip_bfloat16* __restrict__ Wth, const float* __restrict__ bias,
    __hip_bfloat16* __restrict__ Qf, __hip_bfloat16* __restrict__ Kf,
    float* __restrict__ Vf)
{
    const int t   = threadIdx.x;
    const int w   = t >> 6;
    const int l   = t & 63;
    const int lo5 = l & 31, h = l >> 5;
    const int mtile = blockIdx.x * 4 + w;       // 0..511
    const int m0    = mtile * 32;
    const int n_g   = blockIdx.y * 32 + lo5;

    const float* xrow = x + (size_t)(m0 + lo5) * CDIM + 8 * h;
    const __hip_bfloat16* whp = Wth + (size_t)n_g * CDIM + 8 * h;

    f32x16 acc = {};
    #pragma unroll 4
    for (int k0 = 0; k0 < CDIM; k0 += 16) {
        const float4 xa = *reinterpret_cast<const float4*>(xrow + k0);
        const float4 xb = *reinterpret_cast<const float4*>(xrow + k0 + 4);
        const float f[8] = {xa.x, xa.y, xa.z, xa.w, xb.x, xb.y, xb.z, xb.w};
        const bf16x8 xh = cvt8(f);
        const bf16x8 bh = ldg8(whp + k0);
        acc = __builtin_amdgcn_mfma_f32_32x32x16_bf16(xh, bh, acc, 0, 0, 0);
    }

    const float bs = bias[n_g];
    if (n_g < 96) {
        const bool isQ = (n_g < 48);
        const int d  = isQ ? n_g : n_g - 48;
        const int s  = d >> 4;
        const int hf = (d >> 3) & 1;
        __hip_bfloat16* base =
            (isQ ? Qf : Kf) + fragOff(mtile, s, hf) + (d & 7);
        #pragma unroll
        for (int r = 0; r < 16; ++r) {
            const int mrow = (r & 3) + 8 * (r >> 2) + 4 * h;
            float val = acc[r] + bs;
            if (isQ) val *= SCALE_LOG2E;
            base[mrow * 8] = __float2bfloat16(val);
        }
    } else if (n_g < 144) {
        const int d = n_g - 96;
        #pragma unroll
        for (int r = 0; r < 16; ++r) {
            const int m = m0 + (r & 3) + 8 * (r >> 2) + 4 * h;
            Vf[(size_t)m * HD + d] = acc[r] + bs;
        }
    }
}

// ---------------------------------------------------------------------------
// Kernel 2: column softmax denominator + V fold.  8 waves split the q-range.
// Vt tiled [b][ktile][d(64)][32] bf16 = V[k][d] / l_k  (d<48 written only).
// ---------------------------------------------------------------------------
__global__ __launch_bounds__(512) void stats_kernel(
    const __hip_bfloat16* __restrict__ Qf, const __hip_bfloat16* __restrict__ Kf,
    const float* __restrict__ Vf, __hip_bfloat16* __restrict__ Vt)
{
    __shared__ float part[8][32];
    __shared__ float linv[32];

    const int t   = threadIdx.x;
    const int w   = t >> 6;
    const int l   = t & 63;
    const int lo5 = l & 31, h = l >> 5;
    const int b       = blockIdx.y;
    const int ktile_l = blockIdx.x;             // 0..127
    const int ktile   = b * 128 + ktile_l;

    bf16x8 ka[3];
    #pragma unroll
    for (int s = 0; s < 3; ++s)
        ka[s] = ldg8(Kf + fragOff(ktile, s, h) + lo5 * 8);

    float lsum[16];
    #pragma unroll
    for (int r = 0; r < 16; ++r) lsum[r] = 0.0f;

    const int qt0 = b * 128 + w * 16;
    #pragma unroll 2
    for (int qq = 0; qq < 16; ++qq) {
        bf16x8 qb[3];
        #pragma unroll
        for (int s = 0; s < 3; ++s)
            qb[s] = ldg8(Qf + fragOff(qt0 + qq, s, h) + lo5 * 8);
        f32x16 acc = {};
        #pragma unroll
        for (int s = 0; s < 3; ++s)
            acc = __builtin_amdgcn_mfma_f32_32x32x16_bf16(ka[s], qb[s], acc, 0, 0, 0);
        #pragma unroll
        for (int r = 0; r < 16; ++r) lsum[r] += __builtin_amdgcn_exp2f(acc[r]);
    }

    #pragma unroll
    for (int r = 0; r < 16; ++r) {
        lsum[r] += __shfl_xor(lsum[r], 1);
        lsum[r] += __shfl_xor(lsum[r], 2);
        lsum[r] += __shfl_xor(lsum[r], 4);
        lsum[r] += __shfl_xor(lsum[r], 8);
        lsum[r] += __shfl_xor(lsum[r], 16);
    }
    if (lo5 == 0) {
        #pragma unroll
        for (int r = 0; r < 16; ++r)
            part[w][(r & 3) + 8 * (r >> 2) + 4 * h] = lsum[r];
    }
    __syncthreads();
    if (t < 32) {
        float s = 0.0f;
        #pragma unroll
        for (int p = 0; p < 8; ++p) s += part[p][t];
        linv[t] = 1.0f / s;
    }
    __syncthreads();

    // V fold: thread -> (k-pair kp, d = dg and dg+32 if dg<16)
    const int kp = t & 15;
    const int dg = t >> 4;          // 0..31
    const float f0 = linv[2 * kp], f1 = linv[2 * kp + 1];
    __hip_bfloat16* vtb = Vt + (size_t)ktile * 2048;
    const float* vfb = Vf + ((size_t)b * SEQ + ktile_l * 32 + 2 * kp) * HD;
    {
        const int d = dg;
        const float v0 = vfb[d], v1 = vfb[HD + d];
        *reinterpret_cast<unsigned*>(&vtb[d * 32 + 2 * kp]) = pk2(v0 * f0, v1 * f1);
    }
    if (dg < 16) {
        const int d = dg + 32;
        const float v0 = vfb[d], v1 = vfb[HD + d];
        *reinterpret_cast<unsigned*>(&vtb[d * 32 + 2 * kp]) = pk2(v0 * f0, v1 * f1);
    }
}

// ---------------------------------------------------------------------------
// Kernel 3: O[q,d] = sum_k exp2(Shat[q,k]) * Vt[d,k].  8 waves split k-range,
// LDS-reduce; wave 0 writes.
// ---------------------------------------------------------------------------
__global__ __launch_bounds__(512) void pv_kernel(
    const __hip_bfloat16* __restrict__ Qf, const __hip_bfloat16* __restrict__ Kf,
    const __hip_bfloat16* __restrict__ Vt, float* __restrict__ out)
{
    __shared__ float red[7][32][64];

    const int t   = threadIdx.x;
    const int w   = t >> 6;
    const int l   = t & 63;
    const int lo5 = l & 31, h = l >> 5;
    const int b       = blockIdx.y;
    const int qtile_l = blockIdx.x;
    const int qtile   = b * 128 + qtile_l;
    const int q0      = qtile_l * 32;
    const bool islo   = (h == 0);

    bf16x8 qb[3];
    #pragma unroll
    for (int s = 0; s < 3; ++s)
        qb[s] = ldg8(Qf + fragOff(qtile, s, h) + lo5 * 8);

    f32x16 o0 = {}, o1 = {};
    const int kt0 = b * 128 + w * 16;

    #pragma unroll 2
    for (int kk = 0; kk < 16; ++kk) {
        const int ktg = kt0 + kk;
        bf16x8 ka[3];
        #pragma unroll
        for (int s = 0; s < 3; ++s)
            ka[s] = ldg8(Kf + fragOff(ktg, s, h) + lo5 * 8);
        f32x16 acc = {};
        #pragma unroll
        for (int s = 0; s < 3; ++s)
            acc = __builtin_amdgcn_mfma_f32_32x32x16_bf16(ka[s], qb[s], acc, 0, 0, 0);

        float p[16];
        #pragma unroll
        for (int r = 0; r < 16; ++r) p[r] = __builtin_amdgcn_exp2f(acc[r]);

        const unsigned x0 = pk2(p[0],  p[1]),  x1 = pk2(p[2],  p[3]);
        const unsigned y0 = pk2(p[4],  p[5]),  y1 = pk2(p[6],  p[7]);
        const unsigned x2 = pk2(p[8],  p[9]),  x3 = pk2(p[10], p[11]);
        const unsigned y2 = pk2(p[12], p[13]), y3 = pk2(p[14], p[15]);

        unsigned w0, w1, w2, w3, w4, w5, w6, w7;
        { const unsigned ax = __shfl_xor(x0, 32), bx = __shfl_xor(y0, 32);
          w0 = islo ? x0 : bx;  w2 = islo ? ax : y0; }
        { const unsigned ax = __shfl_xor(x1, 32), bx = __shfl_xor(y1, 32);
          w1 = islo ? x1 : bx;  w3 = islo ? ax : y1; }
        { const unsigned ax = __shfl_xor(x2, 32), bx = __shfl_xor(y2, 32);
          w4 = islo ? x2 : bx;  w6 = islo ? ax : y2; }
        { const unsigned ax = __shfl_xor(x3, 32), bx = __shfl_xor(y3, 32);
          w5 = islo ? x3 : bx;  w7 = islo ? ax : y3; }

        const bf16x8 pa0 = mk8(w0, w1, w2, w3);
        const bf16x8 pa1 = mk8(w4, w5, w6, w7);

        const __hip_bfloat16* vt = Vt + (size_t)ktg * 2048 + lo5 * 32 + 8 * h;
        const bf16x8 va  = ldg8(vt);
        const bf16x8 vb2 = ldg8(vt + 16);
        const bf16x8 vc  = ldg8(vt + 1024);
        const bf16x8 vd  = ldg8(vt + 1024 + 16);
        o0 = __builtin_amdgcn_mfma_f32_32x32x16_bf16(pa0, va,  o0, 0, 0, 0);
        o0 = __builtin_amdgcn_mfma_f32_32x32x16_bf16(pa1, vb2, o0, 0, 0, 0);
        o1 = __builtin_amdgcn_mfma_f32_32x32x16_bf16(pa0, vc,  o1, 0, 0, 0);
        o1 = __builtin_amdgcn_mfma_f32_32x32x16_bf16(pa1, vd,  o1, 0, 0, 0);
    }

    if (w > 0) {
        #pragma unroll
        for (int r = 0; r < 16; ++r) {
            red[w - 1][r][l]      = o0[r];
            red[w - 1][16 + r][l] = o1[r];
        }
    }
    __syncthreads();
    if (w == 0) {
        #pragma unroll
        for (int r = 0; r < 16; ++r) {
            #pragma unroll
            for (int p = 0; p < 7; ++p) {
                o0[r] += red[p][r][l];
                o1[r] += red[p][16 + r][l];
            }
        }
        #pragma unroll
        for (int r = 0; r < 16; ++r) {
            const int q = q0 + (r & 3) + 8 * (r >> 2) + 4 * h;
            out[((size_t)(b * SEQ) + q) * HD + lo5] = o0[r];
            if (lo5 < 16)
                out[((size_t)(b * SEQ) + q) * HD + 32 + lo5] = o1[r];
        }
    }
}

// ---------------------------------------------------------------------------
extern "C" void kernel_launch(void* const* d_in, const int* in_sizes, int n_in,
                              void* d_out, int out_size, void* d_ws, size_t ws_size,
                              hipStream_t stream)
{
    const float* x  = (const float*)d_in[0];
    const float* Wq = (const float*)d_in[1];
    const float* bq = (const float*)d_in[2];
    const float* Wk = (const float*)d_in[3];
    const float* bk = (const float*)d_in[4];
    const float* Wv = (const float*)d_in[5];
    const float* bv = (const float*)d_in[6];
    float* out = (float*)d_out;

    const size_t FRAG = (size_t)512 * 6 * 256;                     // 786432 elems
    __hip_bfloat16* Qf  = (__hip_bfloat16*)d_ws;                   // 1.5 MB
    __hip_bfloat16* Kf  = Qf + FRAG;                               // 1.5 MB
    float*          Vf  = (float*)(Kf + FRAG);                     // 3 MB
    __hip_bfloat16* Vt  = (__hip_bfloat16*)(Vf + (size_t)NB * SEQ * HD); // 2 MB
    __hip_bfloat16* Wth = Vt + (size_t)NB * 128 * 2048;            // 240 KB
    float*          bias = (float*)(Wth + (size_t)160 * CDIM);     // 640 B

    prep_kernel<<<dim3(60), 256, 0, stream>>>(Wq, Wk, Wv, bq, bk, bv, Wth, bias);
    proj_kernel<<<dim3(128, 5), 256, 0, stream>>>(x, Wth, bias, Qf, Kf, Vf);
    stats_kernel<<<dim3(128, NB), 512, 0, stream>>>(Qf, Kf, Vf, Vt);
    pv_kernel<<<dim3(128, NB), 512, 0, stream>>>(Qf, Kf, Vt, out);
}

// Round 6
// 67.839 us; speedup vs baseline: 10.1987x; 1.5103x over previous
//
#include <hip/hip_runtime.h>
#include <hip/hip_bf16.h>

#define NB 4
#define SEQ 4096
#define CDIM 768
#define HD 48

typedef __attribute__((ext_vector_type(8))) __bf16 bf16x8;
typedef __attribute__((ext_vector_type(16))) float f32x16;

// (1/sqrt(48)) * log2(e): folded into Q at projection store so P = exp2(S_acc)
static constexpr float SCALE_LOG2E = 0.20823542135164923f;

__device__ __forceinline__ bf16x8 ldg8(const __hip_bfloat16* p) {
    uint4 u = *reinterpret_cast<const uint4*>(p);
    bf16x8 r;
    __builtin_memcpy(&r, &u, 16);
    return r;
}
__device__ __forceinline__ unsigned pk2(float lo, float hi) {
    const __hip_bfloat16 a = __float2bfloat16(lo);
    const __hip_bfloat16 b = __float2bfloat16(hi);
    unsigned short ua, ub;
    __builtin_memcpy(&ua, &a, 2);
    __builtin_memcpy(&ub, &b, 2);
    return (unsigned)ua | ((unsigned)ub << 16);
}
__device__ __forceinline__ bf16x8 mk8(unsigned w0, unsigned w1, unsigned w2, unsigned w3) {
    const uint4 u = make_uint4(w0, w1, w2, w3);
    bf16x8 r;
    __builtin_memcpy(&r, &u, 16);
    return r;
}
// Q/K fragment base offset (elements): frag (tile, s, h) is 256 contiguous bf16
__device__ __forceinline__ size_t fragOff(int tile, int s, int h) {
    return (((size_t)tile * 3 + s) * 2 + h) * 256;
}

// ---------------------------------------------------------------------------
// Kernel 0: prep — Wf in B-fragment-major layout:
//   Wf[nt(5)][ks(48)][l(64)][8] bf16, elem (nt,ks,l,j) = W[ks*16+(l>>5)*8+j][nt*32+(l&31)]
//   cols: 0..47 = Wq, 48..95 = Wk, 96..143 = Wv, 144..159 = 0.  bias[160].
// ---------------------------------------------------------------------------
__global__ __launch_bounds__(256) void prep_kernel(
    const float* __restrict__ Wq, const float* __restrict__ Wk,
    const float* __restrict__ Wv,
    const float* __restrict__ bq, const float* __restrict__ bk,
    const float* __restrict__ bv,
    __hip_bfloat16* __restrict__ Wf, float* __restrict__ bias)
{
    const int g = blockIdx.x * 256 + threadIdx.x;   // 0..15359
    if (g < 15360) {
        const int rem  = g % 3072;
        const int nt   = g / 3072;
        const int ks   = rem >> 6;
        const int l2   = rem & 63;
        const int hh   = l2 >> 5;
        const int lane = l2 & 31;
        const int n    = nt * 32 + lane;
        const float* src = (n < 48) ? Wq : (n < 96) ? Wk : (n < 144) ? Wv : nullptr;
        const int col = (n < 48) ? n : (n < 96) ? (n - 48) : (n - 96);
        #pragma unroll
        for (int j = 0; j < 8; ++j) {
            const int k = ks * 16 + hh * 8 + j;
            const float wv = src ? src[(size_t)k * HD + col] : 0.0f;
            Wf[(size_t)g * 8 + j] = __float2bfloat16(wv);
        }
    }
    if (blockIdx.x == 0 && threadIdx.x < 160) {
        const int t = threadIdx.x;
        bias[t] = (t < 48) ? bq[t] : (t < 96) ? bk[t - 48] : (t < 144) ? bv[t - 96] : 0.0f;
    }
}

// ---------------------------------------------------------------------------
// Kernel 1: proj.  1 block per 32-row m-tile, 5 waves (wave = one 32-col n-tile).
// Stage x rows coalesced-along-k -> A-frag-major LDS (bf16), then
// 48 x { ds_read_b128 A + coalesced global B + MFMA }.
// ---------------------------------------------------------------------------
__global__ __launch_bounds__(320) void proj_kernel(
    const float* __restrict__ x,
    const __hip_bfloat16* __restrict__ Wf, const float* __restrict__ bias,
    __hip_bfloat16* __restrict__ Qf, __hip_bfloat16* __restrict__ Kf,
    float* __restrict__ Vf)
{
    __shared__ __hip_bfloat16 xs[48 * 512];   // [ks][l][8] frag-major, 48 KB

    const int t   = threadIdx.x;
    const int w   = t >> 6;          // wave = n-tile 0..4
    const int l   = t & 63;
    const int lo5 = l & 31, h = l >> 5;
    const int mt  = blockIdx.x;      // 0..511
    const int m0  = mt * 32;

    // stage: 32 rows x 768 k fp32 -> bf16 frag-major.  6144 float4 over 320 thr.
    const float* xb = x + (size_t)m0 * CDIM;
    #pragma unroll
    for (int i = 0; i < 20; ++i) {
        const int c = i * 320 + t;
        if (c < 6144) {
            const int r   = c / 192;
            const int pos = c % 192;
            const int k   = pos * 4;
            const float4 v = *reinterpret_cast<const float4*>(xb + (size_t)r * CDIM + k);
            const int ks = k >> 4, hh = (k >> 3) & 1, j = k & 7;
            const uint2 d = make_uint2(pk2(v.x, v.y), pk2(v.z, v.w));
            *reinterpret_cast<uint2*>(&xs[ks * 512 + (hh * 32 + r) * 8 + j]) = d;
        }
    }
    __syncthreads();

    const __hip_bfloat16* bp = Wf + (size_t)w * 24576 + l * 8;
    f32x16 acc = {};
    #pragma unroll 8
    for (int ks = 0; ks < 48; ++ks) {
        bf16x8 a;
        __builtin_memcpy(&a, &xs[ks * 512 + l * 8], 16);
        const bf16x8 b = ldg8(bp + (size_t)ks * 512);
        acc = __builtin_amdgcn_mfma_f32_32x32x16_bf16(a, b, acc, 0, 0, 0);
    }

    const int n_g = w * 32 + lo5;
    const float bs = bias[n_g];
    if (n_g < 96) {
        const bool isQ = (n_g < 48);
        const int d  = isQ ? n_g : n_g - 48;
        const int s  = d >> 4;
        const int hf = (d >> 3) & 1;
        __hip_bfloat16* base = (isQ ? Qf : Kf) + fragOff(mt, s, hf) + (d & 7);
        #pragma unroll
        for (int r = 0; r < 16; ++r) {
            const int mrow = (r & 3) + 8 * (r >> 2) + 4 * h;
            float val = acc[r] + bs;
            if (isQ) val *= SCALE_LOG2E;
            base[mrow * 8] = __float2bfloat16(val);
        }
    } else if (n_g < 144) {
        const int d = n_g - 96;
        #pragma unroll
        for (int r = 0; r < 16; ++r) {
            const int m = m0 + (r & 3) + 8 * (r >> 2) + 4 * h;
            Vf[(size_t)m * HD + d] = acc[r] + bs;
        }
    }
}

// ---------------------------------------------------------------------------
// Kernel 2: column softmax denominator + V fold.  8 waves split the q-range.
// Vt tiled [b][ktile][d(64)][32] bf16 = V[k][d] / l_k  (d<48 written only).
// ---------------------------------------------------------------------------
__global__ __launch_bounds__(512) void stats_kernel(
    const __hip_bfloat16* __restrict__ Qf, const __hip_bfloat16* __restrict__ Kf,
    const float* __restrict__ Vf, __hip_bfloat16* __restrict__ Vt)
{
    __shared__ float part[8][32];
    __shared__ float linv[32];

    const int t   = threadIdx.x;
    const int w   = t >> 6;
    const int l   = t & 63;
    const int lo5 = l & 31, h = l >> 5;
    const int b       = blockIdx.y;
    const int ktile_l = blockIdx.x;             // 0..127
    const int ktile   = b * 128 + ktile_l;

    bf16x8 ka[3];
    #pragma unroll
    for (int s = 0; s < 3; ++s)
        ka[s] = ldg8(Kf + fragOff(ktile, s, h) + lo5 * 8);

    float lsum[16];
    #pragma unroll
    for (int r = 0; r < 16; ++r) lsum[r] = 0.0f;

    const int qt0 = b * 128 + w * 16;
    #pragma unroll 2
    for (int qq = 0; qq < 16; ++qq) {
        bf16x8 qb[3];
        #pragma unroll
        for (int s = 0; s < 3; ++s)
            qb[s] = ldg8(Qf + fragOff(qt0 + qq, s, h) + lo5 * 8);
        f32x16 acc = {};
        #pragma unroll
        for (int s = 0; s < 3; ++s)
            acc = __builtin_amdgcn_mfma_f32_32x32x16_bf16(ka[s], qb[s], acc, 0, 0, 0);
        #pragma unroll
        for (int r = 0; r < 16; ++r) lsum[r] += __builtin_amdgcn_exp2f(acc[r]);
    }

    #pragma unroll
    for (int r = 0; r < 16; ++r) {
        lsum[r] += __shfl_xor(lsum[r], 1);
        lsum[r] += __shfl_xor(lsum[r], 2);
        lsum[r] += __shfl_xor(lsum[r], 4);
        lsum[r] += __shfl_xor(lsum[r], 8);
        lsum[r] += __shfl_xor(lsum[r], 16);
    }
    if (lo5 == 0) {
        #pragma unroll
        for (int r = 0; r < 16; ++r)
            part[w][(r & 3) + 8 * (r >> 2) + 4 * h] = lsum[r];
    }
    __syncthreads();
    if (t < 32) {
        float s = 0.0f;
        #pragma unroll
        for (int p = 0; p < 8; ++p) s += part[p][t];
        linv[t] = 1.0f / s;
    }
    __syncthreads();

    // V fold: thread -> (k-pair kp, d = dg and dg+32 if dg<16)
    const int kp = t & 15;
    const int dg = t >> 4;          // 0..31
    const float f0 = linv[2 * kp], f1 = linv[2 * kp + 1];
    __hip_bfloat16* vtb = Vt + (size_t)ktile * 2048;
    const float* vfb = Vf + ((size_t)b * SEQ + ktile_l * 32 + 2 * kp) * HD;
    {
        const int d = dg;
        const float v0 = vfb[d], v1 = vfb[HD + d];
        *reinterpret_cast<unsigned*>(&vtb[d * 32 + 2 * kp]) = pk2(v0 * f0, v1 * f1);
    }
    if (dg < 16) {
        const int d = dg + 32;
        const float v0 = vfb[d], v1 = vfb[HD + d];
        *reinterpret_cast<unsigned*>(&vtb[d * 32 + 2 * kp]) = pk2(v0 * f0, v1 * f1);
    }
}

// ---------------------------------------------------------------------------
// Kernel 3: O[q,d] = sum_k exp2(Shat[q,k]) * Vt[d,k].  8 waves split k-range,
// LDS-reduce; wave 0 writes.
// ---------------------------------------------------------------------------
__global__ __launch_bounds__(512) void pv_kernel(
    const __hip_bfloat16* __restrict__ Qf, const __hip_bfloat16* __restrict__ Kf,
    const __hip_bfloat16* __restrict__ Vt, float* __restrict__ out)
{
    __shared__ float red[7][32][64];

    const int t   = threadIdx.x;
    const int w   = t >> 6;
    const int l   = t & 63;
    const int lo5 = l & 31, h = l >> 5;
    const int b       = blockIdx.y;
    const int qtile_l = blockIdx.x;
    const int qtile   = b * 128 + qtile_l;
    const int q0      = qtile_l * 32;
    const bool islo   = (h == 0);

    bf16x8 qb[3];
    #pragma unroll
    for (int s = 0; s < 3; ++s)
        qb[s] = ldg8(Qf + fragOff(qtile, s, h) + lo5 * 8);

    f32x16 o0 = {}, o1 = {};
    const int kt0 = b * 128 + w * 16;

    #pragma unroll 2
    for (int kk = 0; kk < 16; ++kk) {
        const int ktg = kt0 + kk;
        bf16x8 ka[3];
        #pragma unroll
        for (int s = 0; s < 3; ++s)
            ka[s] = ldg8(Kf + fragOff(ktg, s, h) + lo5 * 8);
        f32x16 acc = {};
        #pragma unroll
        for (int s = 0; s < 3; ++s)
            acc = __builtin_amdgcn_mfma_f32_32x32x16_bf16(ka[s], qb[s], acc, 0, 0, 0);

        float p[16];
        #pragma unroll
        for (int r = 0; r < 16; ++r) p[r] = __builtin_amdgcn_exp2f(acc[r]);

        const unsigned x0 = pk2(p[0],  p[1]),  x1 = pk2(p[2],  p[3]);
        const unsigned y0 = pk2(p[4],  p[5]),  y1 = pk2(p[6],  p[7]);
        const unsigned x2 = pk2(p[8],  p[9]),  x3 = pk2(p[10], p[11]);
        const unsigned y2 = pk2(p[12], p[13]), y3 = pk2(p[14], p[15]);

        unsigned w0, w1, w2, w3, w4, w5, w6, w7;
        { const unsigned ax = __shfl_xor(x0, 32), bx = __shfl_xor(y0, 32);
          w0 = islo ? x0 : bx;  w2 = islo ? ax : y0; }
        { const unsigned ax = __shfl_xor(x1, 32), bx = __shfl_xor(y1, 32);
          w1 = islo ? x1 : bx;  w3 = islo ? ax : y1; }
        { const unsigned ax = __shfl_xor(x2, 32), bx = __shfl_xor(y2, 32);
          w4 = islo ? x2 : bx;  w6 = islo ? ax : y2; }
        { const unsigned ax = __shfl_xor(x3, 32), bx = __shfl_xor(y3, 32);
          w5 = islo ? x3 : bx;  w7 = islo ? ax : y3; }

        const bf16x8 pa0 = mk8(w0, w1, w2, w3);
        const bf16x8 pa1 = mk8(w4, w5, w6, w7);

        const __hip_bfloat16* vt = Vt + (size_t)ktg * 2048 + lo5 * 32 + 8 * h;
        const bf16x8 va  = ldg8(vt);
        const bf16x8 vb2 = ldg8(vt + 16);
        const bf16x8 vc  = ldg8(vt + 1024);
        const bf16x8 vd  = ldg8(vt + 1024 + 16);
        o0 = __builtin_amdgcn_mfma_f32_32x32x16_bf16(pa0, va,  o0, 0, 0, 0);
        o0 = __builtin_amdgcn_mfma_f32_32x32x16_bf16(pa1, vb2, o0, 0, 0, 0);
        o1 = __builtin_amdgcn_mfma_f32_32x32x16_bf16(pa0, vc,  o1, 0, 0, 0);
        o1 = __builtin_amdgcn_mfma_f32_32x32x16_bf16(pa1, vd,  o1, 0, 0, 0);
    }

    if (w > 0) {
        #pragma unroll
        for (int r = 0; r < 16; ++r) {
            red[w - 1][r][l]      = o0[r];
            red[w - 1][16 + r][l] = o1[r];
        }
    }
    __syncthreads();
    if (w == 0) {
        #pragma unroll
        for (int r = 0; r < 16; ++r) {
            #pragma unroll
            for (int p = 0; p < 7; ++p) {
                o0[r] += red[p][r][l];
                o1[r] += red[p][16 + r][l];
            }
        }
        #pragma unroll
        for (int r = 0; r < 16; ++r) {
            const int q = q0 + (r & 3) + 8 * (r >> 2) + 4 * h;
            out[((size_t)(b * SEQ) + q) * HD + lo5] = o0[r];
            if (lo5 < 16)
                out[((size_t)(b * SEQ) + q) * HD + 32 + lo5] = o1[r];
        }
    }
}

// ---------------------------------------------------------------------------
extern "C" void kernel_launch(void* const* d_in, const int* in_sizes, int n_in,
                              void* d_out, int out_size, void* d_ws, size_t ws_size,
                              hipStream_t stream)
{
    const float* x  = (const float*)d_in[0];
    const float* Wq = (const float*)d_in[1];
    const float* bq = (const float*)d_in[2];
    const float* Wk = (const float*)d_in[3];
    const float* bk = (const float*)d_in[4];
    const float* Wv = (const float*)d_in[5];
    const float* bv = (const float*)d_in[6];
    float* out = (float*)d_out;

    const size_t FRAG = (size_t)512 * 6 * 256;                     // 786432 elems
    __hip_bfloat16* Qf  = (__hip_bfloat16*)d_ws;                   // 1.5 MB
    __hip_bfloat16* Kf  = Qf + FRAG;                               // 1.5 MB
    float*          Vf  = (float*)(Kf + FRAG);                     // 3 MB
    __hip_bfloat16* Vt  = (__hip_bfloat16*)(Vf + (size_t)NB * SEQ * HD); // 2 MB
    __hip_bfloat16* Wf  = Vt + (size_t)NB * 128 * 2048;            // 240 KB
    float*          bias = (float*)(Wf + (size_t)5 * 48 * 512);    // 640 B

    prep_kernel<<<dim3(60), 256, 0, stream>>>(Wq, Wk, Wv, bq, bk, bv, Wf, bias);
    proj_kernel<<<dim3(512), 320, 0, stream>>>(x, Wf, bias, Qf, Kf, Vf);
    stats_kernel<<<dim3(128, NB), 512, 0, stream>>>(Qf, Kf, Vf, Vt);
    pv_kernel<<<dim3(128, NB), 512, 0, stream>>>(Qf, Kf, Vt, out);
}